// Round 8
// baseline (3184.311 us; speedup 1.0000x reference)
//
#include <hip/hip_runtime.h>

typedef _Float16 h16;
typedef __attribute__((ext_vector_type(8))) _Float16 h16x8;
typedef __attribute__((ext_vector_type(4))) _Float16 h16x4;
typedef __attribute__((ext_vector_type(4))) float f32x4;

#define DEVFN static __device__ __forceinline__

DEVFN void gl_lds16(const void* g, void* l) {
  __builtin_amdgcn_global_load_lds((const __attribute__((address_space(1))) unsigned int*)g,
                                   (__attribute__((address_space(3))) unsigned int*)l, 16, 0, 0);
}
DEVFN void fsplit(float v, h16& hi, h16& lo) { hi = (h16)v; lo = (h16)(v - (float)hi); }
DEVFN float wred(float v) {
  #pragma unroll
  for (int m = 32; m >= 1; m >>= 1) v += __shfl_xor(v, m, 64);
  return v;
}
DEVFN float sigm(float x) { return 1.0f / (1.0f + expf(-x)); }
DEVFN float softpl(float x) { return fmaxf(x, 0.0f) + log1pf(expf(-fabsf(x))); }

enum { EPI_WRITE = 0, EPI_ADD = 1, EPI_SQRELU = 3, EPI_TSPLIT = 4, EPI_SCATTER = 5, EPI_WRITEH = 6 };
// MODE: 0 dense (z=batch) | 1 gather via list[z], compact rows (z=expert/batch)
//       2 single-list scatter, z=K-slice | 5 scatter batched: z=(expert<<2)|kslice
//       6 gather batched: z=(expert<<3)|p  (B slab linear via sBz)

template<bool SPLIT, int EPI, int MODE>
__global__ __launch_bounds__(256, 2) void gemm_k(
    const h16* __restrict__ Ah, const h16* __restrict__ Al, long lda, long sAz,
    const h16* __restrict__ Bh, const h16* __restrict__ Bl, long ldb, long sBz,
    float* __restrict__ C, long ldc, long sCz,
    h16* __restrict__ Oh, h16* __restrict__ Ol, long ldo,
    int K, int nmask, const float* __restrict__ rs, int rsStride,
    const int4* __restrict__ meta, int metaStep,
    const int* __restrict__ lists, int listStep, long sOz)
{
  __shared__ h16 As[(SPLIT ? 2 : 1) * 4096];
  __shared__ h16 Bs[(SPLIT ? 2 : 1) * 4096];
  const int tid = threadIdx.x;
  const int lane = tid & 63, wave = tid >> 6;
  const int wr = wave >> 1, wc = wave & 1;
  const long z = blockIdx.z;
  const long m0 = (long)blockIdx.x * 128, n0 = (long)blockIdx.y * 128;

  int cntv = 0, eSel = 0;
  long koff = 0;
  const int* lst = nullptr;
  if (MODE == 1) {
    const int4 mt = meta[z * metaStep];
    if ((int)m0 >= mt.y) return;
    cntv = mt.x; lst = lists + z * listStep;
  } else if (MODE == 2) {
    const int4 mt = meta[0];
    if ((int)m0 >= mt.y) return;
    cntv = mt.x; lst = lists; koff = z * (long)K;
  } else if (MODE == 5) {
    eSel = (int)(z >> 2);
    const int4 mt = meta[eSel * metaStep];
    if ((int)m0 >= mt.y) return;
    cntv = mt.x; lst = lists + eSel * listStep;
    koff = (long)(z & 3) * K;
  } else if (MODE == 6) {
    eSel = (int)(z >> 3);
    const int4 mt = meta[eSel * metaStep];
    if ((int)m0 >= mt.y) return;
    cntv = mt.x; lst = lists + eSel * listStep;
  }

  long zA = z, zB = z;
  if (MODE == 5) { zA = eSel; zB = eSel; }
  else if (MODE == 6) { zA = eSel; }          // B slab stays linear in z (sBz covers j*512+p*64)
  const h16* pAh = Ah + zA * sAz;
  const h16* pBh = Bh + zB * sBz;
  const h16* pAl = SPLIT ? (Al + zA * sAz) : nullptr;
  const h16* pBl = SPLIT ? (Bl + zB * sBz) : nullptr;
  const int rA = wave * 16 + (lane >> 2);
  const int khalf = (lane & 3) * 8;
  long arow0, arow1;
  if (MODE == 1 || MODE == 6) { arow0 = lst[m0 + rA]; arow1 = lst[m0 + rA + 64]; }
  else if (MODE == 5)         { arow0 = m0 + rA; arow1 = arow0 + 64; }
  else                        { arow0 = m0 + rA; arow1 = arow0 + 64; }
  const long aoff0 = arow0 * lda + khalf + (MODE == 5 ? 0 : koff);
  const long aoff1 = arow1 * lda + khalf + (MODE == 5 ? 0 : koff);
  const long boff = (n0 + rA) * ldb + khalf + koff;
  const long aoffk = (MODE == 5 ? koff : 0);
  h16* lA = &As[wave * 512];
  h16* lB = &Bs[wave * 512];
  const int fr = lane & 15, fq = lane >> 4;

  const f32x4 zero = {0.f, 0.f, 0.f, 0.f};
  f32x4 acc[4][4];
  #pragma unroll
  for (int m = 0; m < 4; m++)
    #pragma unroll
    for (int n = 0; n < 4; n++) acc[m][n] = zero;

  for (int k0 = 0; k0 < K; k0 += 32) {
    gl_lds16(pAh + aoff0 + aoffk + k0, lA);
    gl_lds16(pAh + aoff1 + aoffk + k0, lA + 2048);
    gl_lds16(pBh + boff + k0, lB);
    gl_lds16(pBh + boff + k0 + 64 * ldb, lB + 2048);
    if (SPLIT) {
      gl_lds16(pAl + aoff0 + aoffk + k0, lA + 4096);
      gl_lds16(pAl + aoff1 + aoffk + k0, lA + 4096 + 2048);
      gl_lds16(pBl + boff + k0, lB + 4096);
      gl_lds16(pBl + boff + k0 + 64 * ldb, lB + 4096 + 2048);
    }
    __syncthreads();
    h16x8 af[4], bf[4], afl[4], bfl[4];
    #pragma unroll
    for (int m = 0; m < 4; m++) {
      const int r = (wr * 64 + m * 16 + fr) * 32 + fq * 8;
      af[m] = *(const h16x8*)&As[r];
      if (SPLIT) afl[m] = *(const h16x8*)&As[4096 + r];
    }
    #pragma unroll
    for (int n = 0; n < 4; n++) {
      const int r = (wc * 64 + n * 16 + fr) * 32 + fq * 8;
      bf[n] = *(const h16x8*)&Bs[r];
      if (SPLIT) bfl[n] = *(const h16x8*)&Bs[4096 + r];
    }
    #pragma unroll
    for (int m = 0; m < 4; m++)
      #pragma unroll
      for (int n = 0; n < 4; n++) {
        acc[m][n] = __builtin_amdgcn_mfma_f32_16x16x32_f16(af[m], bf[n], acc[m][n], 0, 0, 0);
        if (SPLIT) {
          acc[m][n] = __builtin_amdgcn_mfma_f32_16x16x32_f16(af[m], bfl[n], acc[m][n], 0, 0, 0);
          acc[m][n] = __builtin_amdgcn_mfma_f32_16x16x32_f16(afl[m], bf[n], acc[m][n], 0, 0, 0);
        }
      }
    __syncthreads();
  }

  #pragma unroll
  for (int m = 0; m < 4; m++) {
    const long lrow = m0 + wr * 64 + m * 16 + fq * 4;
    #pragma unroll
    for (int n = 0; n < 4; n++) {
      const long gcol = n0 + wc * 64 + n * 16 + fr;
      if (nmask && gcol >= nmask) continue;
      if (EPI == EPI_TSPLIT) {
        h16x4 hv, lv;
        #pragma unroll
        for (int i = 0; i < 4; i++) { h16 a, b2; fsplit(acc[m][n][i], a, b2); hv[i] = a; lv[i] = b2; }
        *(h16x4*)&Oh[z * sOz + gcol * ldo + lrow] = hv;
        *(h16x4*)&Ol[z * sOz + gcol * ldo + lrow] = lv;
      } else if (EPI == EPI_WRITEH) {
        #pragma unroll
        for (int i = 0; i < 4; i++)
          Oh[z * sOz + (lrow + i) * ldo + gcol] = (h16)acc[m][n][i];
      } else if (EPI == EPI_SCATTER) {
        #pragma unroll
        for (int i = 0; i < 4; i++) {
          const int slot = (int)lrow + i;
          if (slot >= cntv) continue;
          const int tok = lst[slot];
          const float g = rs[(long)tok * rsStride + (MODE == 5 ? eSel : 0)];
          atomicAdd(&C[(long)tok * ldc + gcol], g * acc[m][n][i]);
        }
      } else {
        float* cp = C + z * sCz + lrow * ldc + gcol;
        #pragma unroll
        for (int i = 0; i < 4; i++) {
          const float v = acc[m][n][i];
          if (EPI == EPI_WRITE) cp[i * ldc] = v;
          else cp[i * ldc] += v;
        }
      }
    }
  }
}

// ---- 256x256 tile, 8 waves / 512 threads, BK=32 ----
// MODE: 0 dense | 3 FFN arena gather (mmap) | 4 FFN arena scatter (mmap, z=K-slice)
template<bool SPLIT, int EPI, int MODE>
__global__ __launch_bounds__(512, 1) void gemm256_k(
    const h16* __restrict__ Ah, const h16* __restrict__ Al, long lda,
    const h16* __restrict__ Bh, const h16* __restrict__ Bl, long ldb, long sBz,
    float* __restrict__ C, long ldc,
    h16* __restrict__ Oh, h16* __restrict__ Ol, long ldo,
    int K, const float* __restrict__ rs, int rsStride,
    const int4* __restrict__ meta, const int* __restrict__ lists, int listStep,
    const int* __restrict__ mmap)
{
  __shared__ h16 As[(SPLIT ? 2 : 1) * 8192];
  __shared__ h16 Bs[(SPLIT ? 2 : 1) * 8192];
  const int tid = threadIdx.x;
  const int lane = tid & 63, wave = tid >> 6;
  const int wr = wave >> 2, wc = wave & 3;          // 2 x 4 waves
  const long m0 = (long)blockIdx.x * 256, n0 = (long)blockIdx.y * 256;

  int cntv = 0, eIdx = 0, eOff = 0;
  long koff = 0;
  const int* lst = nullptr;
  if (MODE == 3 || MODE == 4) {
    if ((int)m0 >= meta[8].x) return;
    eIdx = mmap[blockIdx.x];
    const int4 mt = meta[eIdx];
    cntv = mt.x; eOff = mt.z;
    lst = lists + eIdx * listStep;
    if (MODE == 4) koff = blockIdx.z * (long)K;
  }

  const h16* pAh = Ah;
  const h16* pBh = Bh + (long)eIdx * sBz;
  const h16* pAl = SPLIT ? Al : nullptr;
  const h16* pBl = SPLIT ? (Bl + (long)eIdx * sBz) : nullptr;
  const int rA = (tid >> 2) & 127;                  // == wave*16 + (lane>>2)
  const int khalf = (lane & 3) * 8;
  long arow0, arow1;
  if (MODE == 3) { arow0 = lst[m0 + rA - eOff]; arow1 = lst[m0 + rA + 128 - eOff]; }
  else           { arow0 = m0 + rA; arow1 = arow0 + 128; }
  const long aoff0 = arow0 * lda + khalf + koff;
  const long aoff1 = arow1 * lda + khalf + koff;
  const long boff0 = (n0 + rA) * ldb + khalf + koff;
  const long boff1 = boff0 + 128 * ldb;
  h16* lA = &As[wave * 512];
  h16* lB = &Bs[wave * 512];
  const int fr = lane & 15, fq = lane >> 4;

  const f32x4 zero = {0.f, 0.f, 0.f, 0.f};
  f32x4 acc[8][4];
  #pragma unroll
  for (int m = 0; m < 8; m++)
    #pragma unroll
    for (int n = 0; n < 4; n++) acc[m][n] = zero;

  for (int k0 = 0; k0 < K; k0 += 32) {
    gl_lds16(pAh + aoff0 + k0, lA);
    gl_lds16(pAh + aoff1 + k0, lA + 4096);
    gl_lds16(pBh + boff0 + k0, lB);
    gl_lds16(pBh + boff1 + k0, lB + 4096);
    if (SPLIT) {
      gl_lds16(pAl + aoff0 + k0, lA + 8192);
      gl_lds16(pAl + aoff1 + k0, lA + 8192 + 4096);
      gl_lds16(pBl + boff0 + k0, lB + 8192);
      gl_lds16(pBl + boff1 + k0, lB + 8192 + 4096);
    }
    __syncthreads();
    h16x8 bf[4], bfl[4];
    #pragma unroll
    for (int n = 0; n < 4; n++) {
      const int r = (wc * 64 + n * 16 + fr) * 32 + fq * 8;
      bf[n] = *(const h16x8*)&Bs[r];
      if (SPLIT) bfl[n] = *(const h16x8*)&Bs[8192 + r];
    }
    #pragma unroll
    for (int m = 0; m < 8; m++) {
      const int r = (wr * 128 + m * 16 + fr) * 32 + fq * 8;
      const h16x8 af = *(const h16x8*)&As[r];
      h16x8 afl;
      if (SPLIT) afl = *(const h16x8*)&As[8192 + r];
      #pragma unroll
      for (int n = 0; n < 4; n++) {
        acc[m][n] = __builtin_amdgcn_mfma_f32_16x16x32_f16(af, bf[n], acc[m][n], 0, 0, 0);
        if (SPLIT) {
          acc[m][n] = __builtin_amdgcn_mfma_f32_16x16x32_f16(af, bfl[n], acc[m][n], 0, 0, 0);
          acc[m][n] = __builtin_amdgcn_mfma_f32_16x16x32_f16(afl, bf[n], acc[m][n], 0, 0, 0);
        }
      }
    }
    __syncthreads();
  }

  #pragma unroll
  for (int m = 0; m < 8; m++) {
    const long lrow = m0 + wr * 128 + m * 16 + fq * 4;
    #pragma unroll
    for (int n = 0; n < 4; n++) {
      const long gcol = n0 + wc * 64 + n * 16 + fr;
      if (EPI == EPI_SQRELU) {
        #pragma unroll
        for (int i = 0; i < 4; i++) {
          float v = acc[m][n][i];
          v = v > 0.f ? v * v : 0.f;
          const h16 a = (h16)v;
          Oh[(lrow + i) * ldo + gcol] = a;
          if (Ol) Ol[(lrow + i) * ldo + gcol] = (h16)(v - (float)a);
        }
      } else if (EPI == EPI_SCATTER) {
        #pragma unroll
        for (int i = 0; i < 4; i++) {
          const int slot = (int)lrow + i - eOff;
          if (slot >= cntv) continue;
          const int tok = lst[slot];
          atomicAdd(&C[(long)tok * ldc + gcol], rs[(long)tok * rsStride + eIdx] * acc[m][n][i]);
        }
      } else {
        float* cp = C + lrow * ldc + gcol;
        #pragma unroll
        for (int i = 0; i < 4; i++) cp[i * ldc] = acc[m][n][i];
      }
    }
  }
}

// transpose + fp16 hi/lo split:  in [Kd, Nd] f32 -> out [Nd, Kd] fp16
template<bool LO>
__global__ __launch_bounds__(256) void k_tsplit(
    const float* __restrict__ in, long inZ,
    h16* __restrict__ oh, h16* __restrict__ ol, long outZ, int Kd, int Nd)
{
  __shared__ float t[64][65];
  const long z = blockIdx.z;
  in += z * inZ; oh += z * outZ; if (LO) ol += z * outZ;
  const int n0 = blockIdx.x * 64, k0 = blockIdx.y * 64;
  const int tr = threadIdx.x >> 4, tc = threadIdx.x & 15;
  #pragma unroll
  for (int r = 0; r < 4; r++) {
    const int row = r * 16 + tr;
    const float4 v = *(const float4*)&in[(long)(k0 + row) * Nd + n0 + tc * 4];
    t[row][tc * 4 + 0] = v.x; t[row][tc * 4 + 1] = v.y;
    t[row][tc * 4 + 2] = v.z; t[row][tc * 4 + 3] = v.w;
  }
  __syncthreads();
  #pragma unroll
  for (int r = 0; r < 4; r++) {
    const int nrow = r * 16 + tr;
    h16x4 hv, lv;
    #pragma unroll
    for (int i = 0; i < 4; i++) {
      h16 a, b2; fsplit(t[tc * 4 + i][nrow], a, b2);
      hv[i] = a; lv[i] = b2;
    }
    *(h16x4*)&oh[(long)(n0 + nrow) * Kd + k0 + tc * 4] = hv;
    if (LO) *(h16x4*)&ol[(long)(n0 + nrow) * Kd + k0 + tc * 4] = lv;
  }
}

// 4-source batched transpose-split: z selects (segment = z>>2 + inAdd) of src[z&3];
// out segment index = z.  in/out segment size = Kd*Nd.
template<bool LO>
__global__ __launch_bounds__(256) void k_tsplit4(
    const float* __restrict__ s0, const float* __restrict__ s1,
    const float* __restrict__ s2, const float* __restrict__ s3,
    long inAdd, h16* __restrict__ oh, h16* __restrict__ ol, int Kd, int Nd)
{
  __shared__ float t[64][65];
  const int z = blockIdx.z;
  const long seg = (long)Kd * Nd;
  const int w = z & 3;
  const float* in = (w == 0 ? s0 : w == 1 ? s1 : w == 2 ? s2 : s3) + (inAdd + (z >> 2)) * seg;
  oh += (long)z * seg; if (LO) ol += (long)z * seg;
  const int n0 = blockIdx.x * 64, k0 = blockIdx.y * 64;
  const int tr = threadIdx.x >> 4, tc = threadIdx.x & 15;
  #pragma unroll
  for (int r = 0; r < 4; r++) {
    const int row = r * 16 + tr;
    const float4 v = *(const float4*)&in[(long)(k0 + row) * Nd + n0 + tc * 4];
    t[row][tc * 4 + 0] = v.x; t[row][tc * 4 + 1] = v.y;
    t[row][tc * 4 + 2] = v.z; t[row][tc * 4 + 3] = v.w;
  }
  __syncthreads();
  #pragma unroll
  for (int r = 0; r < 4; r++) {
    const int nrow = r * 16 + tr;
    h16x4 hv, lv;
    #pragma unroll
    for (int i = 0; i < 4; i++) {
      h16 a, b2; fsplit(t[tc * 4 + i][nrow], a, b2);
      hv[i] = a; lv[i] = b2;
    }
    *(h16x4*)&oh[(long)(n0 + nrow) * Kd + k0 + tc * 4] = hv;
    if (LO) *(h16x4*)&ol[(long)(n0 + nrow) * Kd + k0 + tc * 4] = lv;
  }
}

__global__ void k_split(const float* __restrict__ in, h16* __restrict__ oh, h16* __restrict__ ol)
{
  const long i = (long)blockIdx.x * 256 + threadIdx.x;
  const float4 v = ((const float4*)in)[i];
  h16x4 hv, lv; h16 a, b2;
  fsplit(v.x, a, b2); hv[0] = a; lv[0] = b2;
  fsplit(v.y, a, b2); hv[1] = a; lv[1] = b2;
  fsplit(v.z, a, b2); hv[2] = a; lv[2] = b2;
  fsplit(v.w, a, b2); hv[3] = a; lv[3] = b2;
  ((h16x4*)oh)[i] = hv; ((h16x4*)ol)[i] = lv;
}

__global__ void k_embed(const int* __restrict__ idx, const float* __restrict__ emb, float* __restrict__ x)
{
  const int row = blockIdx.x;
  const long e = (long)idx[row] * 1024;
  ((float4*)(x + (long)row * 1024))[threadIdx.x] = ((const float4*)(emb + e))[threadIdx.x];
}

__global__ __launch_bounds__(256) void k_ln(
    const float* __restrict__ x, const float* __restrict__ g, const float* __restrict__ b,
    float* __restrict__ yf, h16* __restrict__ yh, h16* __restrict__ yl)
{
  const int row = blockIdx.x, tid = threadIdx.x;
  const float4 v = ((const float4*)(x + (long)row * 1024))[tid];
  __shared__ float red[4];
  const int wv = tid >> 6;
  float s = wred(v.x + v.y + v.z + v.w);
  if ((tid & 63) == 0) red[wv] = s;
  __syncthreads();
  const float mean = (red[0] + red[1] + red[2] + red[3]) * (1.0f / 1024.0f);
  const float d0 = v.x - mean, d1 = v.y - mean, d2 = v.z - mean, d3 = v.w - mean;
  float s2 = wred(d0 * d0 + d1 * d1 + d2 * d2 + d3 * d3);
  __syncthreads();
  if ((tid & 63) == 0) red[wv] = s2;
  __syncthreads();
  const float var = (red[0] + red[1] + red[2] + red[3]) * (1.0f / 1024.0f);
  const float rstd = 1.0f / sqrtf(var + 1e-5f);
  const float4 gv = ((const float4*)g)[tid];
  const float4 bv = ((const float4*)b)[tid];
  const float y0 = d0 * rstd * gv.x + bv.x;
  const float y1 = d1 * rstd * gv.y + bv.y;
  const float y2 = d2 * rstd * gv.z + bv.z;
  const float y3 = d3 * rstd * gv.w + bv.w;
  if (yf) { float4 o; o.x = y0; o.y = y1; o.z = y2; o.w = y3; ((float4*)(yf + (long)row * 1024))[tid] = o; }
  h16x4 hv, lv; h16 a, b2;
  fsplit(y0, a, b2); hv[0] = a; lv[0] = b2;
  fsplit(y1, a, b2); hv[1] = a; lv[1] = b2;
  fsplit(y2, a, b2); hv[2] = a; lv[2] = b2;
  fsplit(y3, a, b2); hv[3] = a; lv[3] = b2;
  *(h16x4*)(yh + (long)row * 1024 + tid * 4) = hv;
  if (yl) *(h16x4*)(yl + (long)row * 1024 + tid * 4) = lv;
}

// vfir handling on strided rkv layout: mode 0 -> vfir = v;  mode 1 -> v = 0.5*(v+vfir)
__global__ void k_vfix(float* __restrict__ rkv, float* __restrict__ vfir, int mode)
{
  const int row = blockIdx.x, tid = threadIdx.x;
  float4* vp = (float4*)(rkv + (long)row * 3072 + 2048) + tid;
  float4* fp = (float4*)(vfir + (long)row * 1024) + tid;
  if (mode == 0) *fp = *vp;
  else {
    float4 a = *vp; const float4 b = *fp;
    a.x = 0.5f * (a.x + b.x); a.y = 0.5f * (a.y + b.y);
    a.z = 0.5f * (a.z + b.z); a.w = 0.5f * (a.w + b.w);
    *vp = a;
  }
}

// ---- chunked scan over rkv layout: k at +1024, v at +2048, row stride 3072 ----
__global__ __launch_bounds__(256) void k_scan1(const float* __restrict__ rkv,
                                               const float* __restrict__ dec, float* __restrict__ carry)
{
  const int gid = blockIdx.x * 256 + threadIdx.x;   // 65536
  const int c = gid & 1023, bb = (gid >> 10) & 3, ch = gid >> 12;
  const float w = sigm(dec[c]);
  float s = 0.f;
  const long base = ((long)bb * 1024 + ch * 64) * 3072 + c;
  const float* kp_ = rkv + 1024 + base;
  const float* vp_ = rkv + 2048 + base;
  for (int t = 0; t < 64; t++) s = w * s + kp_[(long)t * 3072] * vp_[(long)t * 3072];
  carry[(ch * 4 + bb) * 1024 + c] = s;
}
__global__ void k_scan2(const float* __restrict__ dec, float* __restrict__ carry)
{
  const int gid = blockIdx.x * 256 + threadIdx.x;   // 4096
  const int c = gid & 1023, bb = gid >> 10;
  const float w = sigm(dec[c]);
  float w64 = w;
  for (int i = 0; i < 6; i++) w64 *= w64;
  float s = 0.f;
  for (int j = 0; j < 16; j++) {
    const int o = (j * 4 + bb) * 1024 + c;
    const float a = carry[o];
    carry[o] = s;
    s = w64 * s + a;
  }
}
__global__ __launch_bounds__(256) void k_scan3(const float* __restrict__ rkv,
                                               const float* __restrict__ dec, const float* __restrict__ carry,
                                               float* __restrict__ st)
{
  const int gid = blockIdx.x * 256 + threadIdx.x;
  const int c = gid & 1023, bb = (gid >> 10) & 3, ch = gid >> 12;
  const float w = sigm(dec[c]);
  float s = carry[(ch * 4 + bb) * 1024 + c];
  const long base = ((long)bb * 1024 + ch * 64) * 3072 + c;
  const float* kp_ = rkv + 1024 + base;
  const float* vp_ = rkv + 2048 + base;
  float* so = st + ((long)bb * 1024 + ch * 64) * 1024 + c;
  for (int t = 0; t < 64; t++) {
    s = w * s + kp_[(long)t * 3072] * vp_[(long)t * 3072];
    so[(long)t * 1024] = s;
  }
}

__global__ void k_attin(const float* __restrict__ rkv, const float* __restrict__ s,
                        h16* __restrict__ oh, h16* __restrict__ ol)
{
  const int row = blockIdx.x, tid = threadIdx.x;
  const float4 rv = *((const float4*)(rkv + (long)row * 3072) + tid);
  const float4 sv = *((const float4*)(s + (long)row * 1024) + tid);
  h16x4 hv, lv; h16 a, b2;
  fsplit(sv.x * sigm(rv.x), a, b2); hv[0] = a; lv[0] = b2;
  fsplit(sv.y * sigm(rv.y), a, b2); hv[1] = a; lv[1] = b2;
  fsplit(sv.z * sigm(rv.z), a, b2); hv[2] = a; lv[2] = b2;
  fsplit(sv.w * sigm(rv.w), a, b2); hv[3] = a; lv[3] = b2;
  const long i = (long)row * 256 + tid;
  ((h16x4*)oh)[i] = hv; ((h16x4*)ol)[i] = lv;
}

__global__ void k_addsplit(const float* __restrict__ p, const float* __restrict__ q,
                           h16* __restrict__ oh, h16* __restrict__ ol)
{
  const long i = (long)blockIdx.x * 256 + threadIdx.x;
  const float4 av = ((const float4*)p)[i];
  const float4 bv = ((const float4*)q)[i];
  h16x4 hv, lv; h16 a, b2;
  fsplit(av.x + bv.x, a, b2); hv[0] = a; lv[0] = b2;
  fsplit(av.y + bv.y, a, b2); hv[1] = a; lv[1] = b2;
  fsplit(av.z + bv.z, a, b2); hv[2] = a; lv[2] = b2;
  fsplit(av.w + bv.w, a, b2); hv[3] = a; lv[3] = b2;
  ((h16x4*)oh)[i] = hv; ((h16x4*)ol)[i] = lv;
}

// routing: bids -> top2 -> softmax weights -> gate[4096][8]
__global__ __launch_bounds__(256) void k_route(
    const float* __restrict__ h, const float* __restrict__ cr, const float* __restrict__ ct,
    const float* __restrict__ wd, const float* __restrict__ wa,
    const float* __restrict__ cap, float* __restrict__ gate)
{
  const int wv = threadIdx.x >> 6, ln = threadIdx.x & 63;
  const int row = blockIdx.x * 4 + wv;
  const float* hr = h + (long)row * 1024;
  float hreg[16];
  #pragma unroll
  for (int i = 0; i < 4; i++) {
    const float4 t = ((const float4*)hr)[ln * 4 + i];
    hreg[i * 4 + 0] = t.x; hreg[i * 4 + 1] = t.y; hreg[i * 4 + 2] = t.z; hreg[i * 4 + 3] = t.w;
  }
  float dots[17];
  #pragma unroll
  for (int e = 0; e < 6; e++) {
    float p = 0.f;
    #pragma unroll
    for (int j = 0; j < 16; j++) p += hreg[j] * cr[e * 1024 + ln * 16 + j];
    dots[e] = p;
  }
  #pragma unroll
  for (int e = 0; e < 2; e++) {
    float p = 0.f;
    #pragma unroll
    for (int j = 0; j < 16; j++) p += hreg[j] * ct[e * 1024 + ln * 16 + j];
    dots[6 + e] = p;
  }
  {
    float p = 0.f;
    #pragma unroll
    for (int j = 0; j < 16; j++) p += hreg[j] * wd[ln * 16 + j];
    dots[8] = p;
  }
  #pragma unroll
  for (int e = 0; e < 8; e++) {
    float p = 0.f;
    #pragma unroll
    for (int j = 0; j < 16; j++) p += hreg[j] * wa[(ln * 16 + j) * 8 + e];
    dots[9 + e] = p;
  }
  #pragma unroll
  for (int d = 0; d < 17; d++) dots[d] = wred(dots[d]);
  if (ln == 0) {
    float bids[8];
    const float diff = softpl(dots[8]);
    #pragma unroll
    for (int e = 0; e < 6; e++) bids[e] = sigm(dots[e]) * cap[e] * diff + tanhf(dots[9 + e]);
    #pragma unroll
    for (int e = 0; e < 2; e++) bids[6 + e] = sigm(dots[6 + e]) * cap[6 + e] * diff + tanhf(dots[15 + e]);
    int w0 = 0;
    for (int e = 1; e < 8; e++) if (bids[e] > bids[w0]) w0 = e;
    int w1 = -1;
    for (int e = 0; e < 8; e++) if (e != w0 && (w1 < 0 || bids[e] > bids[w1])) w1 = e;
    const float e1 = expf(bids[w1] - bids[w0]);
    const float q0 = 1.0f / (1.0f + e1), q1 = e1 / (1.0f + e1);
    for (int e = 0; e < 8; e++) gate[(long)row * 8 + e] = (e == w0) ? q0 : ((e == w1) ? q1 : 0.0f);
  }
}

// build per-expert token lists
__global__ void k_build(const float* __restrict__ gate, int* __restrict__ cnt, int* __restrict__ lists)
{
  const int t = blockIdx.x * 256 + threadIdx.x;     // 4096
  #pragma unroll
  for (int e = 0; e < 8; e++)
    if (gate[(long)t * 8 + e] > 0.f) { const int s = atomicAdd(&cnt[e], 1); lists[e * 4224 + s] = t; }
}
// meta[e] = {cnt, cnt_pad256, arenaRowOff (FFN only), 0}; meta[8].x = totalArenaRows; mmap: 256-m-block -> expert
__global__ void k_meta(const int* __restrict__ cnt, int4* __restrict__ meta, int* __restrict__ lists,
                       int* __restrict__ mmap)
{
  __shared__ int sc[8], sp[8], so[8];
  if (threadIdx.x == 0) {
    int acc = 0;
    for (int e = 0; e < 8; e++) {
      const int c = cnt[e], p = (c + 255) & ~255;
      sc[e] = c; sp[e] = p; so[e] = (e < 6) ? acc : 0;
      if (e < 6) acc += p;
    }
    meta[8] = make_int4(acc, 0, 0, 0);
    for (int b = 0; b < 64; b++) mmap[b] = 0;
    for (int e = 0; e < 6; e++)
      for (int b = so[e] >> 8; b < (so[e] + sp[e]) >> 8; b++) mmap[b] = e;
  }
  __syncthreads();
  const int e = threadIdx.x >> 5, i = threadIdx.x & 31;
  for (int s = sc[e] + i; s < sp[e]; s += 32) lists[e * 4224 + s] = 0;
  if (i == 0) meta[e] = make_int4(sc[e], sp[e], so[e], 0);
}

// attn[slot,h,p] = softmax_p( q[slot,h,:].kp[p-slab][slot,hd] / 8 ), kp h16 slabs of stride M4
__global__ __launch_bounds__(256) void k_scores(const float* __restrict__ q, const h16* __restrict__ kp,
                                                float* __restrict__ attn, const int4* __restrict__ meta)
{
  const int gw = blockIdx.x * 4 + (threadIdx.x >> 6), ln = threadIdx.x & 63;
  const int n = gw >> 4, hh = gw & 15;
  if (n >= meta->y) return;
  const float qv = q[(long)n * 1024 + hh * 64 + ln];
  float s[8];
  #pragma unroll
  for (int p = 0; p < 8; p++) {
    float t = qv * (float)kp[(long)p * 4194304 + (long)n * 1024 + hh * 64 + ln];
    s[p] = wred(t) * 0.125f;
  }
  if (ln == 0) {
    float mx = s[0];
    #pragma unroll
    for (int p = 1; p < 8; p++) mx = fmaxf(mx, s[p]);
    float ex[8], sum = 0.f;
    #pragma unroll
    for (int p = 0; p < 8; p++) { ex[p] = expf(s[p] - mx); sum += ex[p]; }
    const float inv = 1.0f / sum;
    #pragma unroll
    for (int p = 0; p < 8; p++) attn[(long)n * 128 + hh * 8 + p] = ex[p] * inv;
  }
}

// o[slot,hd] = sum_p attn[slot,h,p]*vp[p-slab][slot,hd] -> h16 (non-split chain)
__global__ void k_omix2(const float* __restrict__ attn, const h16* __restrict__ vp,
                        h16* __restrict__ oh, const int4* __restrict__ meta)
{
  const long gid = (long)blockIdx.x * 256 + threadIdx.x;  // 4M
  const int n = gid >> 10, hd = gid & 1023, hh = hd >> 6;
  if (n >= meta->y) return;
  const float* a = attn + (long)n * 128 + hh * 8;
  float o = 0.f;
  #pragma unroll
  for (int p = 0; p < 8; p++) o += a[p] * (float)vp[(long)p * 4194304 + (long)n * 1024 + hd];
  oh[gid] = (h16)o;
}

#define GEMM3(SPL, EPI, MODE, GRID, ...) do { \
  if (SPL) gemm_k<true,  EPI, MODE><<<GRID, 256, 0, stream>>>(__VA_ARGS__); \
  else     gemm_k<false, EPI, MODE><<<GRID, 256, 0, stream>>>(__VA_ARGS__); } while (0)
#define GEMM256(SPL, EPI, MODE, GRID, ...) do { \
  if (SPL) gemm256_k<true,  EPI, MODE><<<GRID, 512, 0, stream>>>(__VA_ARGS__); \
  else     gemm256_k<false, EPI, MODE><<<GRID, 512, 0, stream>>>(__VA_ARGS__); } while (0)

extern "C" void kernel_launch(void* const* d_in, const int* in_sizes, int n_in,
                              void* d_out, int out_size, void* d_ws, size_t ws_size,
                              hipStream_t stream)
{
  (void)in_sizes; (void)n_in; (void)out_size; (void)ws_size;
  const int*   idx   = (const int*)  d_in[0];
  const float* cap   = (const float*)d_in[1];
  const float* emb   = (const float*)d_in[2];
  const float* headw = (const float*)d_in[3];
  const float* ln1g  = (const float*)d_in[4];
  const float* ln1b  = (const float*)d_in[5];
  const float* ln2g  = (const float*)d_in[6];
  const float* ln2b  = (const float*)d_in[7];
  const float* lnog  = (const float*)d_in[8];
  const float* lnob  = (const float*)d_in[9];
  const float* aWr   = (const float*)d_in[10];
  const float* aWk   = (const float*)d_in[11];
  const float* aWv   = (const float*)d_in[12];
  const float* aWo   = (const float*)d_in[13];
  const float* adec  = (const float*)d_in[14];
  const float* cwd   = (const float*)d_in[15];
  const float* cWa   = (const float*)d_in[16];
  const float* bWd   = (const float*)d_in[17];
  const float* bWu   = (const float*)d_in[18];
  const float* eWkw  = (const float*)d_in[19];
  const float* eWvw  = (const float*)d_in[20];
  const float* confr = (const float*)d_in[21];
  const float* tWq   = (const float*)d_in[22];
  const float* tWkk  = (const float*)d_in[23];
  const float* tWv   = (const float*)d_in[24];
  const float* tWo   = (const float*)d_in[25];
  const float* conft = (const float*)d_in[26];
  float* out = (float*)d_out;

  char* ws = (char*)d_ws;
  size_t off = 0;
  auto alloc = [&](size_t n) -> char* {
    off = (off + 255) & ~(size_t)255;
    char* p = ws + off; off += n; return p;
  };
  const long M1 = 1048576, M4 = 4194304;

  h16* attWh = (h16*)alloc(8 * M1 * 2);
  h16* attWl = (h16*)alloc(8 * M1 * 2);
  h16* eWkh  = (h16*)alloc(12 * M4 * 2);
  h16* eWkl  = (h16*)alloc(6 * M4 * 2);
  h16* eWvh  = (h16*)alloc(12 * M4 * 2);
  h16* eWvl  = (h16*)alloc(6 * M4 * 2);
  h16* tWh   = (h16*)alloc(16 * M1 * 2);     // layout: [lj=0..3][mat: q,k,v,o]
  h16* headh = (h16*)alloc(32768000ull * 2);
  h16* wdh   = (h16*)alloc(131072 * 2);
  h16* wuph  = (h16*)alloc(524288 * 2);
  h16* wupl  = (h16*)alloc(524288 * 2);
  h16* foldKh = (h16*)alloc(1048576 * 2);    // [hd=1024][j*512 + p*64 + r]
  h16* foldKl = (h16*)alloc(1048576 * 2);
  h16* foldVh = (h16*)alloc(1048576 * 2);
  h16* foldVl = (h16*)alloc(1048576 * 2);
  h16* s1h   = (h16*)alloc(2 * M4 * 2);      // seg 0 general; seg j for o-outputs
  h16* s1l   = (h16*)alloc(M4 * 2);
  h16* hh_   = (h16*)alloc(M4 * 2);
  h16* hl_   = (h16*)alloc(M4 * 2);
  h16* uh    = (h16*)alloc(262144 * 2);
  h16* ul    = (h16*)alloc(262144 * 2);
  float* x    = (float*)alloc(M4 * 4);
  float* vfir = (float*)alloc(M4 * 4);
  float* rkv  = (float*)alloc(3 * M4 * 4);        // fused r|k|v, [4096][3072]
  float* st   = (float*)alloc(M4 * 4);
  float* hf   = (float*)alloc(M4 * 4);
  float* qf   = (float*)alloc(2 * M4 * 4);        // q per transformer expert j
  char* big   = alloc(167772160);                 // 160MB union: hid hi/lo arena | kp/vp h16 slabs
  h16* hidh   = (h16*)big;                        // <=9984 rows x 4096 x 2B = 78MB
  h16* hidl   = (h16*)(big + 83886080ull);        // offset 80MiB
  h16* kpH    = (h16*)big;                        // 16 slabs x M4 h16 = 128MB
  float* carry = (float*)alloc(65536 * 4);
  float* gate  = (float*)alloc(32768 * 4);
  float* uf    = (float*)alloc(262144 * 4);
  float* attn  = (float*)alloc(2 * 524288 * 4);
  int*   cnt8  = (int*)alloc(32);
  int4*  metaA = (int4*)alloc(16 * 16);
  int*   lists = (int*)alloc(8 * 4224 * 4);
  int*   mmap  = (int*)alloc(64 * 4);

  // ---------- weight conversion ----------
  k_tsplit4<true><<<dim3(16, 16, 8), 256, 0, stream>>>(aWr, aWk, aWv, aWo, 0, attWh, attWl, 1024, 1024);
  k_tsplit<true ><<<dim3(64, 16, 6), 256, 0, stream>>>(eWkw, M4, eWkh, eWkl, M4, 1024, 4096);
  k_tsplit<false><<<dim3(64, 16, 6), 256, 0, stream>>>(eWkw + 6 * M4, M4, eWkh + 6 * M4, nullptr, M4, 1024, 4096);
  k_tsplit<true ><<<dim3(16, 64, 6), 256, 0, stream>>>(eWvw, M4, eWvh, eWvl, M4, 4096, 1024);
  k_tsplit<false><<<dim3(16, 64, 6), 256, 0, stream>>>(eWvw + 6 * M4, M4, eWvh + 6 * M4, nullptr, M4, 4096, 1024);
  k_tsplit4<false><<<dim3(16, 16, 16), 256, 0, stream>>>(tWq, tWkk, tWv, tWo, 0, tWh, nullptr, 1024, 1024);
  k_tsplit<false><<<dim3(500, 16, 1), 256, 0, stream>>>(headw, 0, headh, nullptr, 0, 1024, 32000);
  k_tsplit<false><<<dim3(1, 16, 1), 256, 0, stream>>>(bWd, 0, wdh, nullptr, 0, 1024, 64);
  hipMemsetAsync(wdh + 65536, 0, 65536 * 2, stream);   // pad Bt rows 64..127 with zeros
  k_split<<<512, 256, 0, stream>>>(bWu, wuph, wupl);

  // ---------- forward ----------
  k_embed<<<4096, 256, 0, stream>>>(idx, emb, x);

  for (int l = 0; l < 2; l++) {
    const bool SE = (l == 0);           // FFN expert path split only on layer 0
    // --- TimeMix (split: feeds routing); fused r|k|v GEMM, N=3072 ---
    k_ln<<<4096, 256, 0, stream>>>(x, ln1g + l * 1024, ln1b + l * 1024, nullptr, s1h, s1l);
    GEMM3(true, EPI_WRITE, 0, dim3(32, 24),
          s1h, s1l, 1024, 0, attWh + (l * 4) * M1, attWl + (l * 4) * M1, 1024, 0,
          rkv, 3072, 0, nullptr, nullptr, 0, 1024, 0, nullptr, 0, nullptr, 0, nullptr, 0, 0);
    k_vfix<<<4096, 256, 0, stream>>>(rkv, vfir, l == 0 ? 0 : 1);
    k_scan1<<<256, 256, 0, stream>>>(rkv, adec + l * 1024, carry);
    k_scan2<<<16, 256, 0, stream>>>(adec + l * 1024, carry);
    k_scan3<<<256, 256, 0, stream>>>(rkv, adec + l * 1024, carry, st);
    k_attin<<<4096, 256, 0, stream>>>(rkv, st, s1h, s1l);
    GEMM3(true, EPI_ADD, 0, dim3(32, 8),
          s1h, s1l, 1024, 0, attWh + (l * 4 + 3) * M1, attWl + (l * 4 + 3) * M1, 1024, 0,
          x, 1024, 0, nullptr, nullptr, 0, 1024, 0, nullptr, 0, nullptr, 0, nullptr, 0, 0);
    // --- routing + token lists ---
    k_ln<<<4096, 256, 0, stream>>>(x, ln2g + l * 1024, ln2b + l * 1024, hf, hh_, hl_);
    k_route<<<1024, 256, 0, stream>>>(hf, confr + l * 6144, conft + l * 2048, cwd + l * 1024, cWa + l * 8192, cap + l * 8, gate);
    hipMemsetAsync(cnt8, 0, 32, stream);
    k_build<<<16, 256, 0, stream>>>(gate, cnt8, lists);
    k_meta<<<1, 256, 0, stream>>>(cnt8, metaA, lists, mmap);
    // --- bridge: u = (h + state) @ Wdown (non-split) ---
    k_addsplit<<<4096, 256, 0, stream>>>(hf, st, s1h, s1l);
    GEMM3(false, EPI_WRITE, 0, dim3(32, 1),
          s1h, nullptr, 1024, 0, wdh, nullptr, 1024, 0,
          uf, 64, 0, nullptr, nullptr, 0, 1024, 64, nullptr, 0, nullptr, 0, nullptr, 0, 0);
    k_split<<<256, 256, 0, stream>>>(uf, uh, ul);
    // --- FFN experts: 256-tile arena gather->sqrelu, then 256-tile split-K(8) scatter ---
    GEMM256(SE, EPI_SQRELU, 3, dim3(40, 16),
            hh_, hl_, 1024, eWkh + l * 6 * M4, eWkl, 1024, M4,
            nullptr, 0, hidh, SE ? hidl : nullptr, 4096,
            1024, nullptr, 0, metaA, lists, 4224, mmap);
    GEMM256(SE, EPI_SCATTER, 4, dim3(40, 4, 8),
            hidh, hidl, 4096, eWvh + l * 6 * M4, eWvl, 4096, M4,
            x, 1024, nullptr, nullptr, 0,
            512, gate, 8, metaA, lists, 4224, mmap);
    // --- transformer experts, batched over j (non-split chain) ---
    // folds: K and V, each z=2 over j -> foldK/V [hd][j*512+p*64+r]
    GEMM3(false, EPI_TSPLIT, 0, dim3(4, 8, 2),
          wuph, nullptr, 1024, 0, tWh + (l * 8 + 1) * M1, nullptr, 1024, 4 * M1,
          nullptr, 0, 0, foldKh, foldKl, 1024, 1024, 0, nullptr, 0, nullptr, 0, nullptr, 0, 512);
    GEMM3(false, EPI_TSPLIT, 0, dim3(4, 8, 2),
          wuph, nullptr, 1024, 0, tWh + (l * 8 + 2) * M1, nullptr, 1024, 4 * M1,
          nullptr, 0, 0, foldVh, foldVl, 1024, 1024, 0, nullptr, 0, nullptr, 0, nullptr, 0, 512);
    // q for both j: z=2 (MODE 1, per-z meta/list)
    GEMM3(false, EPI_WRITE, 1, dim3(32, 8, 2),
          hh_, nullptr, 1024, 0, tWh + (l * 8 + 0) * M1, nullptr, 1024, 4 * M1,
          qf, 1024, M4, nullptr, nullptr, 0, 1024, 0, nullptr, 0,
          metaA + 6, 1, lists + 6 * 4224, 4224, 0);
    // kp for both j: z=16 (MODE 6), h16 slabs [z][slot][hd]
    GEMM3(false, EPI_WRITEH, 6, dim3(32, 8, 16),
          uh, nullptr, 64, 0, foldKh, nullptr, 1024, 64,
          nullptr, 0, 0, kpH, nullptr, 1024, 64, 0, nullptr, 0,
          metaA + 6, 1, lists + 6 * 4224, 4224, M4);
    for (int j = 0; j < 2; j++)
      k_scores<<<16384, 256, 0, stream>>>(qf + (long)j * M4, kpH + (long)j * 8 * M4,
                                          attn + (long)j * 524288, metaA + 6 + j);
    // vp for both j (overwrites kpH)
    GEMM3(false, EPI_WRITEH, 6, dim3(32, 8, 16),
          uh, nullptr, 64, 0, foldVh, nullptr, 1024, 64,
          nullptr, 0, 0, kpH, nullptr, 1024, 64, 0, nullptr, 0,
          metaA + 6, 1, lists + 6 * 4224, 4224, M4);
    for (int j = 0; j < 2; j++)
      k_omix2<<<16384, 256, 0, stream>>>(attn + (long)j * 524288, kpH + (long)j * 8 * M4,
                                         s1h + (long)j * M4, metaA + 6 + j);
    // x[tok] += gate * (o @ tWo): both j + 4 K-slices in one dispatch (MODE 5)
    GEMM3(false, EPI_SCATTER, 5, dim3(32, 8, 8),
          s1h, nullptr, 1024, M4, tWh + (l * 8 + 3) * M1, nullptr, 1024, 4 * M1,
          x, 1024, 0, nullptr, nullptr, 0, 256, 0, gate + 6, 8,
          metaA + 6, 1, lists + 6 * 4224, 4224, 0);
  }

  // --- final LN + head (plain fp16, 128-tile: best measured config) ---
  k_ln<<<4096, 256, 0, stream>>>(x, lnog, lnob, nullptr, s1h, s1l);
  GEMM3(false, EPI_WRITE, 0, dim3(32, 250),
        s1h, nullptr, 1024, 0, headh, nullptr, 1024, 0,
        out, 32000, 0, nullptr, nullptr, 0, 1024, 0, nullptr, 0, nullptr, 0, nullptr, 0, 0);
}

// Round 9
// 2854.492 us; speedup vs baseline: 1.1155x; 1.1155x over previous
//
#include <hip/hip_runtime.h>

typedef _Float16 h16;
typedef __attribute__((ext_vector_type(8))) _Float16 h16x8;
typedef __attribute__((ext_vector_type(4))) _Float16 h16x4;
typedef __attribute__((ext_vector_type(4))) float f32x4;

#define DEVFN static __device__ __forceinline__

DEVFN void gl_lds16(const void* g, void* l) {
  __builtin_amdgcn_global_load_lds((const __attribute__((address_space(1))) unsigned int*)g,
                                   (__attribute__((address_space(3))) unsigned int*)l, 16, 0, 0);
}
DEVFN void fsplit(float v, h16& hi, h16& lo) { hi = (h16)v; lo = (h16)(v - (float)hi); }
DEVFN float wred(float v) {
  #pragma unroll
  for (int m = 32; m >= 1; m >>= 1) v += __shfl_xor(v, m, 64);
  return v;
}
DEVFN float sigm(float x) { return 1.0f / (1.0f + expf(-x)); }
DEVFN float softpl(float x) { return fmaxf(x, 0.0f) + log1pf(expf(-fabsf(x))); }

enum { EPI_WRITE = 0, EPI_ADD = 1, EPI_SQRELU = 3, EPI_TSPLIT = 4, EPI_SCATTER = 5, EPI_WRITEH = 6 };
// MODE: 0 dense (z=batch) | 1 gather via list[z], compact rows (z=expert/batch)
//       2 single-list scatter, z=K-slice | 5 scatter batched: z=(expert<<2)|kslice
//       6 gather batched: z=(expert<<3)|p  (B slab linear via sBz)

template<bool SPLIT, int EPI, int MODE>
__global__ __launch_bounds__(256, 2) void gemm_k(
    const h16* __restrict__ Ah, const h16* __restrict__ Al, long lda, long sAz,
    const h16* __restrict__ Bh, const h16* __restrict__ Bl, long ldb, long sBz,
    float* __restrict__ C, long ldc, long sCz,
    h16* __restrict__ Oh, h16* __restrict__ Ol, long ldo,
    int K, int nmask, const float* __restrict__ rs, int rsStride,
    const int4* __restrict__ meta, int metaStep,
    const int* __restrict__ lists, int listStep, long sOz)
{
  __shared__ h16 As[(SPLIT ? 2 : 1) * 4096];
  __shared__ h16 Bs[(SPLIT ? 2 : 1) * 4096];
  const int tid = threadIdx.x;
  const int lane = tid & 63, wave = tid >> 6;
  const int wr = wave >> 1, wc = wave & 1;
  const long z = blockIdx.z;
  const long m0 = (long)blockIdx.x * 128, n0 = (long)blockIdx.y * 128;

  int cntv = 0, eSel = 0;
  long koff = 0;
  const int* lst = nullptr;
  if (MODE == 1) {
    const int4 mt = meta[z * metaStep];
    if ((int)m0 >= mt.y) return;
    cntv = mt.x; lst = lists + z * listStep;
  } else if (MODE == 2) {
    const int4 mt = meta[0];
    if ((int)m0 >= mt.y) return;
    cntv = mt.x; lst = lists; koff = z * (long)K;
  } else if (MODE == 5) {
    eSel = (int)(z >> 2);
    const int4 mt = meta[eSel * metaStep];
    if ((int)m0 >= mt.y) return;
    cntv = mt.x; lst = lists + eSel * listStep;
    koff = (long)(z & 3) * K;
  } else if (MODE == 6) {
    eSel = (int)(z >> 3);
    const int4 mt = meta[eSel * metaStep];
    if ((int)m0 >= mt.y) return;
    cntv = mt.x; lst = lists + eSel * listStep;
  }

  long zA = z, zB = z;
  if (MODE == 5) { zA = eSel; zB = eSel; }
  else if (MODE == 6) { zA = eSel; }          // B slab stays linear in z (sBz covers j*512+p*64)
  const h16* pAh = Ah + zA * sAz;
  const h16* pBh = Bh + zB * sBz;
  const h16* pAl = SPLIT ? (Al + zA * sAz) : nullptr;
  const h16* pBl = SPLIT ? (Bl + zB * sBz) : nullptr;
  const int rA = wave * 16 + (lane >> 2);
  const int khalf = (lane & 3) * 8;
  long arow0, arow1;
  if (MODE == 1 || MODE == 6) { arow0 = lst[m0 + rA]; arow1 = lst[m0 + rA + 64]; }
  else if (MODE == 5)         { arow0 = m0 + rA; arow1 = arow0 + 64; }
  else                        { arow0 = m0 + rA; arow1 = arow0 + 64; }
  const long aoff0 = arow0 * lda + khalf + (MODE == 5 ? 0 : koff);
  const long aoff1 = arow1 * lda + khalf + (MODE == 5 ? 0 : koff);
  const long boff = (n0 + rA) * ldb + khalf + koff;
  const long aoffk = (MODE == 5 ? koff : 0);
  h16* lA = &As[wave * 512];
  h16* lB = &Bs[wave * 512];
  const int fr = lane & 15, fq = lane >> 4;

  const f32x4 zero = {0.f, 0.f, 0.f, 0.f};
  f32x4 acc[4][4];
  #pragma unroll
  for (int m = 0; m < 4; m++)
    #pragma unroll
    for (int n = 0; n < 4; n++) acc[m][n] = zero;

  for (int k0 = 0; k0 < K; k0 += 32) {
    gl_lds16(pAh + aoff0 + aoffk + k0, lA);
    gl_lds16(pAh + aoff1 + aoffk + k0, lA + 2048);
    gl_lds16(pBh + boff + k0, lB);
    gl_lds16(pBh + boff + k0 + 64 * ldb, lB + 2048);
    if (SPLIT) {
      gl_lds16(pAl + aoff0 + aoffk + k0, lA + 4096);
      gl_lds16(pAl + aoff1 + aoffk + k0, lA + 4096 + 2048);
      gl_lds16(pBl + boff + k0, lB + 4096);
      gl_lds16(pBl + boff + k0 + 64 * ldb, lB + 4096 + 2048);
    }
    __syncthreads();
    h16x8 af[4], bf[4], afl[4], bfl[4];
    #pragma unroll
    for (int m = 0; m < 4; m++) {
      const int r = (wr * 64 + m * 16 + fr) * 32 + fq * 8;
      af[m] = *(const h16x8*)&As[r];
      if (SPLIT) afl[m] = *(const h16x8*)&As[4096 + r];
    }
    #pragma unroll
    for (int n = 0; n < 4; n++) {
      const int r = (wc * 64 + n * 16 + fr) * 32 + fq * 8;
      bf[n] = *(const h16x8*)&Bs[r];
      if (SPLIT) bfl[n] = *(const h16x8*)&Bs[4096 + r];
    }
    #pragma unroll
    for (int m = 0; m < 4; m++)
      #pragma unroll
      for (int n = 0; n < 4; n++) {
        acc[m][n] = __builtin_amdgcn_mfma_f32_16x16x32_f16(af[m], bf[n], acc[m][n], 0, 0, 0);
        if (SPLIT) {
          acc[m][n] = __builtin_amdgcn_mfma_f32_16x16x32_f16(af[m], bfl[n], acc[m][n], 0, 0, 0);
          acc[m][n] = __builtin_amdgcn_mfma_f32_16x16x32_f16(afl[m], bf[n], acc[m][n], 0, 0, 0);
        }
      }
    __syncthreads();
  }

  #pragma unroll
  for (int m = 0; m < 4; m++) {
    const long lrow = m0 + wr * 64 + m * 16 + fq * 4;
    #pragma unroll
    for (int n = 0; n < 4; n++) {
      const long gcol = n0 + wc * 64 + n * 16 + fr;
      if (nmask && gcol >= nmask) continue;
      if (EPI == EPI_TSPLIT) {
        h16x4 hv, lv;
        #pragma unroll
        for (int i = 0; i < 4; i++) { h16 a, b2; fsplit(acc[m][n][i], a, b2); hv[i] = a; lv[i] = b2; }
        *(h16x4*)&Oh[z * sOz + gcol * ldo + lrow] = hv;
        *(h16x4*)&Ol[z * sOz + gcol * ldo + lrow] = lv;
      } else if (EPI == EPI_WRITEH) {
        #pragma unroll
        for (int i = 0; i < 4; i++)
          Oh[z * sOz + (lrow + i) * ldo + gcol] = (h16)acc[m][n][i];
      } else if (EPI == EPI_SCATTER) {
        #pragma unroll
        for (int i = 0; i < 4; i++) {
          const int slot = (int)lrow + i;
          if (slot >= cntv) continue;
          const int tok = lst[slot];
          const float g = rs[(long)tok * rsStride + (MODE == 5 ? eSel : 0)];
          atomicAdd(&C[(long)tok * ldc + gcol], g * acc[m][n][i]);
        }
      } else {
        float* cp = C + z * sCz + lrow * ldc + gcol;
        #pragma unroll
        for (int i = 0; i < 4; i++) {
          const float v = acc[m][n][i];
          if (EPI == EPI_WRITE) cp[i * ldc] = v;
          else cp[i * ldc] += v;
        }
      }
    }
  }
}

// ---- 256x256 tile, 8 waves / 512 threads, BK=32 ----
// MODE: 0 dense | 3 FFN arena gather (mmap) | 4 FFN arena scatter (mmap, z=K-slice)
template<bool SPLIT, int EPI, int MODE>
__global__ __launch_bounds__(512, 1) void gemm256_k(
    const h16* __restrict__ Ah, const h16* __restrict__ Al, long lda,
    const h16* __restrict__ Bh, const h16* __restrict__ Bl, long ldb, long sBz,
    float* __restrict__ C, long ldc,
    h16* __restrict__ Oh, h16* __restrict__ Ol, long ldo,
    int K, const float* __restrict__ rs, int rsStride,
    const int4* __restrict__ meta, const int* __restrict__ lists, int listStep,
    const int* __restrict__ mmap)
{
  __shared__ h16 As[(SPLIT ? 2 : 1) * 8192];
  __shared__ h16 Bs[(SPLIT ? 2 : 1) * 8192];
  const int tid = threadIdx.x;
  const int lane = tid & 63, wave = tid >> 6;
  const int wr = wave >> 2, wc = wave & 3;          // 2 x 4 waves
  const long m0 = (long)blockIdx.x * 256, n0 = (long)blockIdx.y * 256;

  int cntv = 0, eIdx = 0, eOff = 0;
  long koff = 0;
  const int* lst = nullptr;
  if (MODE == 3 || MODE == 4) {
    if ((int)m0 >= meta[8].x) return;
    eIdx = mmap[blockIdx.x];
    const int4 mt = meta[eIdx];
    cntv = mt.x; eOff = mt.z;
    lst = lists + eIdx * listStep;
    if (MODE == 4) koff = blockIdx.z * (long)K;
  }

  const h16* pAh = Ah;
  const h16* pBh = Bh + (long)eIdx * sBz;
  const h16* pAl = SPLIT ? Al : nullptr;
  const h16* pBl = SPLIT ? (Bl + (long)eIdx * sBz) : nullptr;
  const int rA = (tid >> 2) & 127;                  // == wave*16 + (lane>>2)
  const int khalf = (lane & 3) * 8;
  long arow0, arow1;
  if (MODE == 3) { arow0 = lst[m0 + rA - eOff]; arow1 = lst[m0 + rA + 128 - eOff]; }
  else           { arow0 = m0 + rA; arow1 = arow0 + 128; }
  const long aoff0 = arow0 * lda + khalf + koff;
  const long aoff1 = arow1 * lda + khalf + koff;
  const long boff0 = (n0 + rA) * ldb + khalf + koff;
  const long boff1 = boff0 + 128 * ldb;
  h16* lA = &As[wave * 512];
  h16* lB = &Bs[wave * 512];
  const int fr = lane & 15, fq = lane >> 4;

  const f32x4 zero = {0.f, 0.f, 0.f, 0.f};
  f32x4 acc[8][4];
  #pragma unroll
  for (int m = 0; m < 8; m++)
    #pragma unroll
    for (int n = 0; n < 4; n++) acc[m][n] = zero;

  for (int k0 = 0; k0 < K; k0 += 32) {
    gl_lds16(pAh + aoff0 + k0, lA);
    gl_lds16(pAh + aoff1 + k0, lA + 4096);
    gl_lds16(pBh + boff0 + k0, lB);
    gl_lds16(pBh + boff1 + k0, lB + 4096);
    if (SPLIT) {
      gl_lds16(pAl + aoff0 + k0, lA + 8192);
      gl_lds16(pAl + aoff1 + k0, lA + 8192 + 4096);
      gl_lds16(pBl + boff0 + k0, lB + 8192);
      gl_lds16(pBl + boff1 + k0, lB + 8192 + 4096);
    }
    __syncthreads();
    h16x8 bf[4], bfl[4];
    #pragma unroll
    for (int n = 0; n < 4; n++) {
      const int r = (wc * 64 + n * 16 + fr) * 32 + fq * 8;
      bf[n] = *(const h16x8*)&Bs[r];
      if (SPLIT) bfl[n] = *(const h16x8*)&Bs[8192 + r];
    }
    #pragma unroll
    for (int m = 0; m < 8; m++) {
      const int r = (wr * 128 + m * 16 + fr) * 32 + fq * 8;
      const h16x8 af = *(const h16x8*)&As[r];
      h16x8 afl;
      if (SPLIT) afl = *(const h16x8*)&As[8192 + r];
      #pragma unroll
      for (int n = 0; n < 4; n++) {
        acc[m][n] = __builtin_amdgcn_mfma_f32_16x16x32_f16(af, bf[n], acc[m][n], 0, 0, 0);
        if (SPLIT) {
          acc[m][n] = __builtin_amdgcn_mfma_f32_16x16x32_f16(af, bfl[n], acc[m][n], 0, 0, 0);
          acc[m][n] = __builtin_amdgcn_mfma_f32_16x16x32_f16(afl, bf[n], acc[m][n], 0, 0, 0);
        }
      }
    }
    __syncthreads();
  }

  #pragma unroll
  for (int m = 0; m < 8; m++) {
    const long lrow = m0 + wr * 128 + m * 16 + fq * 4;
    #pragma unroll
    for (int n = 0; n < 4; n++) {
      const long gcol = n0 + wc * 64 + n * 16 + fr;
      if (EPI == EPI_SQRELU) {
        #pragma unroll
        for (int i = 0; i < 4; i++) {
          float v = acc[m][n][i];
          v = v > 0.f ? v * v : 0.f;
          const h16 a = (h16)v;
          Oh[(lrow + i) * ldo + gcol] = a;
          if (Ol) Ol[(lrow + i) * ldo + gcol] = (h16)(v - (float)a);
        }
      } else if (EPI == EPI_SCATTER) {
        #pragma unroll
        for (int i = 0; i < 4; i++) {
          const int slot = (int)lrow + i - eOff;
          if (slot >= cntv) continue;
          const int tok = lst[slot];
          atomicAdd(&C[(long)tok * ldc + gcol], rs[(long)tok * rsStride + eIdx] * acc[m][n][i]);
        }
      } else {
        float* cp = C + lrow * ldc + gcol;
        #pragma unroll
        for (int i = 0; i < 4; i++) cp[i * ldc] = acc[m][n][i];
      }
    }
  }
}

// transpose + fp16 hi/lo split:  in [Kd, Nd] f32 -> out [Nd, Kd] fp16
template<bool LO>
__global__ __launch_bounds__(256) void k_tsplit(
    const float* __restrict__ in, long inZ,
    h16* __restrict__ oh, h16* __restrict__ ol, long outZ, int Kd, int Nd)
{
  __shared__ float t[64][65];
  const long z = blockIdx.z;
  in += z * inZ; oh += z * outZ; if (LO) ol += z * outZ;
  const int n0 = blockIdx.x * 64, k0 = blockIdx.y * 64;
  const int tr = threadIdx.x >> 4, tc = threadIdx.x & 15;
  #pragma unroll
  for (int r = 0; r < 4; r++) {
    const int row = r * 16 + tr;
    const float4 v = *(const float4*)&in[(long)(k0 + row) * Nd + n0 + tc * 4];
    t[row][tc * 4 + 0] = v.x; t[row][tc * 4 + 1] = v.y;
    t[row][tc * 4 + 2] = v.z; t[row][tc * 4 + 3] = v.w;
  }
  __syncthreads();
  #pragma unroll
  for (int r = 0; r < 4; r++) {
    const int nrow = r * 16 + tr;
    h16x4 hv, lv;
    #pragma unroll
    for (int i = 0; i < 4; i++) {
      h16 a, b2; fsplit(t[tc * 4 + i][nrow], a, b2);
      hv[i] = a; lv[i] = b2;
    }
    *(h16x4*)&oh[(long)(n0 + nrow) * Kd + k0 + tc * 4] = hv;
    if (LO) *(h16x4*)&ol[(long)(n0 + nrow) * Kd + k0 + tc * 4] = lv;
  }
}

// 4-source batched transpose-split: z selects (segment = z>>2 + inAdd) of src[z&3];
// out segment index = z.  in/out segment size = Kd*Nd.
template<bool LO>
__global__ __launch_bounds__(256) void k_tsplit4(
    const float* __restrict__ s0, const float* __restrict__ s1,
    const float* __restrict__ s2, const float* __restrict__ s3,
    long inAdd, h16* __restrict__ oh, h16* __restrict__ ol, int Kd, int Nd)
{
  __shared__ float t[64][65];
  const int z = blockIdx.z;
  const long seg = (long)Kd * Nd;
  const int w = z & 3;
  const float* in = (w == 0 ? s0 : w == 1 ? s1 : w == 2 ? s2 : s3) + (inAdd + (z >> 2)) * seg;
  oh += (long)z * seg; if (LO) ol += (long)z * seg;
  const int n0 = blockIdx.x * 64, k0 = blockIdx.y * 64;
  const int tr = threadIdx.x >> 4, tc = threadIdx.x & 15;
  #pragma unroll
  for (int r = 0; r < 4; r++) {
    const int row = r * 16 + tr;
    const float4 v = *(const float4*)&in[(long)(k0 + row) * Nd + n0 + tc * 4];
    t[row][tc * 4 + 0] = v.x; t[row][tc * 4 + 1] = v.y;
    t[row][tc * 4 + 2] = v.z; t[row][tc * 4 + 3] = v.w;
  }
  __syncthreads();
  #pragma unroll
  for (int r = 0; r < 4; r++) {
    const int nrow = r * 16 + tr;
    h16x4 hv, lv;
    #pragma unroll
    for (int i = 0; i < 4; i++) {
      h16 a, b2; fsplit(t[tc * 4 + i][nrow], a, b2);
      hv[i] = a; lv[i] = b2;
    }
    *(h16x4*)&oh[(long)(n0 + nrow) * Kd + k0 + tc * 4] = hv;
    if (LO) *(h16x4*)&ol[(long)(n0 + nrow) * Kd + k0 + tc * 4] = lv;
  }
}

__global__ void k_split(const float* __restrict__ in, h16* __restrict__ oh, h16* __restrict__ ol)
{
  const long i = (long)blockIdx.x * 256 + threadIdx.x;
  const float4 v = ((const float4*)in)[i];
  h16x4 hv, lv; h16 a, b2;
  fsplit(v.x, a, b2); hv[0] = a; lv[0] = b2;
  fsplit(v.y, a, b2); hv[1] = a; lv[1] = b2;
  fsplit(v.z, a, b2); hv[2] = a; lv[2] = b2;
  fsplit(v.w, a, b2); hv[3] = a; lv[3] = b2;
  ((h16x4*)oh)[i] = hv; ((h16x4*)ol)[i] = lv;
}

__global__ void k_embed(const int* __restrict__ idx, const float* __restrict__ emb, float* __restrict__ x)
{
  const int row = blockIdx.x;
  const long e = (long)idx[row] * 1024;
  ((float4*)(x + (long)row * 1024))[threadIdx.x] = ((const float4*)(emb + e))[threadIdx.x];
}

__global__ __launch_bounds__(256) void k_ln(
    const float* __restrict__ x, const float* __restrict__ g, const float* __restrict__ b,
    float* __restrict__ yf, h16* __restrict__ yh, h16* __restrict__ yl)
{
  const int row = blockIdx.x, tid = threadIdx.x;
  const float4 v = ((const float4*)(x + (long)row * 1024))[tid];
  __shared__ float red[4];
  const int wv = tid >> 6;
  float s = wred(v.x + v.y + v.z + v.w);
  if ((tid & 63) == 0) red[wv] = s;
  __syncthreads();
  const float mean = (red[0] + red[1] + red[2] + red[3]) * (1.0f / 1024.0f);
  const float d0 = v.x - mean, d1 = v.y - mean, d2 = v.z - mean, d3 = v.w - mean;
  float s2 = wred(d0 * d0 + d1 * d1 + d2 * d2 + d3 * d3);
  __syncthreads();
  if ((tid & 63) == 0) red[wv] = s2;
  __syncthreads();
  const float var = (red[0] + red[1] + red[2] + red[3]) * (1.0f / 1024.0f);
  const float rstd = 1.0f / sqrtf(var + 1e-5f);
  const float4 gv = ((const float4*)g)[tid];
  const float4 bv = ((const float4*)b)[tid];
  const float y0 = d0 * rstd * gv.x + bv.x;
  const float y1 = d1 * rstd * gv.y + bv.y;
  const float y2 = d2 * rstd * gv.z + bv.z;
  const float y3 = d3 * rstd * gv.w + bv.w;
  if (yf) { float4 o; o.x = y0; o.y = y1; o.z = y2; o.w = y3; ((float4*)(yf + (long)row * 1024))[tid] = o; }
  h16x4 hv, lv; h16 a, b2;
  fsplit(y0, a, b2); hv[0] = a; lv[0] = b2;
  fsplit(y1, a, b2); hv[1] = a; lv[1] = b2;
  fsplit(y2, a, b2); hv[2] = a; lv[2] = b2;
  fsplit(y3, a, b2); hv[3] = a; lv[3] = b2;
  *(h16x4*)(yh + (long)row * 1024 + tid * 4) = hv;
  if (yl) *(h16x4*)(yl + (long)row * 1024 + tid * 4) = lv;
}

// vfir handling on strided rkv layout: mode 0 -> vfir = v;  mode 1 -> v = 0.5*(v+vfir)
__global__ void k_vfix(float* __restrict__ rkv, float* __restrict__ vfir, int mode)
{
  const int row = blockIdx.x, tid = threadIdx.x;
  float4* vp = (float4*)(rkv + (long)row * 3072 + 2048) + tid;
  float4* fp = (float4*)(vfir + (long)row * 1024) + tid;
  if (mode == 0) *fp = *vp;
  else {
    float4 a = *vp; const float4 b = *fp;
    a.x = 0.5f * (a.x + b.x); a.y = 0.5f * (a.y + b.y);
    a.z = 0.5f * (a.z + b.z); a.w = 0.5f * (a.w + b.w);
    *vp = a;
  }
}

// ---- chunked scan over rkv layout: k at +1024, v at +2048, row stride 3072 ----
__global__ __launch_bounds__(256) void k_scan1(const float* __restrict__ rkv,
                                               const float* __restrict__ dec, float* __restrict__ carry)
{
  const int gid = blockIdx.x * 256 + threadIdx.x;   // 65536
  const int c = gid & 1023, bb = (gid >> 10) & 3, ch = gid >> 12;
  const float w = sigm(dec[c]);
  float s = 0.f;
  const long base = ((long)bb * 1024 + ch * 64) * 3072 + c;
  const float* kp_ = rkv + 1024 + base;
  const float* vp_ = rkv + 2048 + base;
  for (int t = 0; t < 64; t++) s = w * s + kp_[(long)t * 3072] * vp_[(long)t * 3072];
  carry[(ch * 4 + bb) * 1024 + c] = s;
}
__global__ void k_scan2(const float* __restrict__ dec, float* __restrict__ carry)
{
  const int gid = blockIdx.x * 256 + threadIdx.x;   // 4096
  const int c = gid & 1023, bb = gid >> 10;
  const float w = sigm(dec[c]);
  float w64 = w;
  for (int i = 0; i < 6; i++) w64 *= w64;
  float s = 0.f;
  for (int j = 0; j < 16; j++) {
    const int o = (j * 4 + bb) * 1024 + c;
    const float a = carry[o];
    carry[o] = s;
    s = w64 * s + a;
  }
}
__global__ __launch_bounds__(256) void k_scan3(const float* __restrict__ rkv,
                                               const float* __restrict__ dec, const float* __restrict__ carry,
                                               float* __restrict__ st)
{
  const int gid = blockIdx.x * 256 + threadIdx.x;
  const int c = gid & 1023, bb = (gid >> 10) & 3, ch = gid >> 12;
  const float w = sigm(dec[c]);
  float s = carry[(ch * 4 + bb) * 1024 + c];
  const long base = ((long)bb * 1024 + ch * 64) * 3072 + c;
  const float* kp_ = rkv + 1024 + base;
  const float* vp_ = rkv + 2048 + base;
  float* so = st + ((long)bb * 1024 + ch * 64) * 1024 + c;
  for (int t = 0; t < 64; t++) {
    s = w * s + kp_[(long)t * 3072] * vp_[(long)t * 3072];
    so[(long)t * 1024] = s;
  }
}

__global__ void k_attin(const float* __restrict__ rkv, const float* __restrict__ s,
                        h16* __restrict__ oh, h16* __restrict__ ol)
{
  const int row = blockIdx.x, tid = threadIdx.x;
  const float4 rv = *((const float4*)(rkv + (long)row * 3072) + tid);
  const float4 sv = *((const float4*)(s + (long)row * 1024) + tid);
  h16x4 hv, lv; h16 a, b2;
  fsplit(sv.x * sigm(rv.x), a, b2); hv[0] = a; lv[0] = b2;
  fsplit(sv.y * sigm(rv.y), a, b2); hv[1] = a; lv[1] = b2;
  fsplit(sv.z * sigm(rv.z), a, b2); hv[2] = a; lv[2] = b2;
  fsplit(sv.w * sigm(rv.w), a, b2); hv[3] = a; lv[3] = b2;
  const long i = (long)row * 256 + tid;
  ((h16x4*)oh)[i] = hv; ((h16x4*)ol)[i] = lv;
}

__global__ void k_addsplit(const float* __restrict__ p, const float* __restrict__ q,
                           h16* __restrict__ oh, h16* __restrict__ ol)
{
  const long i = (long)blockIdx.x * 256 + threadIdx.x;
  const float4 av = ((const float4*)p)[i];
  const float4 bv = ((const float4*)q)[i];
  h16x4 hv, lv; h16 a, b2;
  fsplit(av.x + bv.x, a, b2); hv[0] = a; lv[0] = b2;
  fsplit(av.y + bv.y, a, b2); hv[1] = a; lv[1] = b2;
  fsplit(av.z + bv.z, a, b2); hv[2] = a; lv[2] = b2;
  fsplit(av.w + bv.w, a, b2); hv[3] = a; lv[3] = b2;
  ((h16x4*)oh)[i] = hv; ((h16x4*)ol)[i] = lv;
}

// routing: bids -> top2 -> softmax weights -> gate[4096][8]
__global__ __launch_bounds__(256) void k_route(
    const float* __restrict__ h, const float* __restrict__ cr, const float* __restrict__ ct,
    const float* __restrict__ wd, const float* __restrict__ wa,
    const float* __restrict__ cap, float* __restrict__ gate)
{
  const int wv = threadIdx.x >> 6, ln = threadIdx.x & 63;
  const int row = blockIdx.x * 4 + wv;
  const float* hr = h + (long)row * 1024;
  float hreg[16];
  #pragma unroll
  for (int i = 0; i < 4; i++) {
    const float4 t = ((const float4*)hr)[ln * 4 + i];
    hreg[i * 4 + 0] = t.x; hreg[i * 4 + 1] = t.y; hreg[i * 4 + 2] = t.z; hreg[i * 4 + 3] = t.w;
  }
  float dots[17];
  #pragma unroll
  for (int e = 0; e < 6; e++) {
    float p = 0.f;
    #pragma unroll
    for (int j = 0; j < 16; j++) p += hreg[j] * cr[e * 1024 + ln * 16 + j];
    dots[e] = p;
  }
  #pragma unroll
  for (int e = 0; e < 2; e++) {
    float p = 0.f;
    #pragma unroll
    for (int j = 0; j < 16; j++) p += hreg[j] * ct[e * 1024 + ln * 16 + j];
    dots[6 + e] = p;
  }
  {
    float p = 0.f;
    #pragma unroll
    for (int j = 0; j < 16; j++) p += hreg[j] * wd[ln * 16 + j];
    dots[8] = p;
  }
  #pragma unroll
  for (int e = 0; e < 8; e++) {
    float p = 0.f;
    #pragma unroll
    for (int j = 0; j < 16; j++) p += hreg[j] * wa[(ln * 16 + j) * 8 + e];
    dots[9 + e] = p;
  }
  #pragma unroll
  for (int d = 0; d < 17; d++) dots[d] = wred(dots[d]);
  if (ln == 0) {
    float bids[8];
    const float diff = softpl(dots[8]);
    #pragma unroll
    for (int e = 0; e < 6; e++) bids[e] = sigm(dots[e]) * cap[e] * diff + tanhf(dots[9 + e]);
    #pragma unroll
    for (int e = 0; e < 2; e++) bids[6 + e] = sigm(dots[6 + e]) * cap[6 + e] * diff + tanhf(dots[15 + e]);
    int w0 = 0;
    for (int e = 1; e < 8; e++) if (bids[e] > bids[w0]) w0 = e;
    int w1 = -1;
    for (int e = 0; e < 8; e++) if (e != w0 && (w1 < 0 || bids[e] > bids[w1])) w1 = e;
    const float e1 = expf(bids[w1] - bids[w0]);
    const float q0 = 1.0f / (1.0f + e1), q1 = e1 / (1.0f + e1);
    for (int e = 0; e < 8; e++) gate[(long)row * 8 + e] = (e == w0) ? q0 : ((e == w1) ? q1 : 0.0f);
  }
}

// build per-expert token lists
__global__ void k_build(const float* __restrict__ gate, int* __restrict__ cnt, int* __restrict__ lists)
{
  const int t = blockIdx.x * 256 + threadIdx.x;     // 4096
  #pragma unroll
  for (int e = 0; e < 8; e++)
    if (gate[(long)t * 8 + e] > 0.f) { const int s = atomicAdd(&cnt[e], 1); lists[e * 4224 + s] = t; }
}
// meta[e] = {cnt, cnt_pad256, arenaRowOff (FFN only), 0}; meta[8].x = totalArenaRows; mmap: 256-m-block -> expert
__global__ void k_meta(const int* __restrict__ cnt, int4* __restrict__ meta, int* __restrict__ lists,
                       int* __restrict__ mmap)
{
  __shared__ int sc[8], sp[8], so[8];
  if (threadIdx.x == 0) {
    int acc = 0;
    for (int e = 0; e < 8; e++) {
      const int c = cnt[e], p = (c + 255) & ~255;
      sc[e] = c; sp[e] = p; so[e] = (e < 6) ? acc : 0;
      if (e < 6) acc += p;
    }
    meta[8] = make_int4(acc, 0, 0, 0);
    for (int b = 0; b < 64; b++) mmap[b] = 0;
    for (int e = 0; e < 6; e++)
      for (int b = so[e] >> 8; b < (so[e] + sp[e]) >> 8; b++) mmap[b] = e;
  }
  __syncthreads();
  const int e = threadIdx.x >> 5, i = threadIdx.x & 31;
  for (int s = sc[e] + i; s < sp[e]; s += 32) lists[e * 4224 + s] = 0;
  if (i == 0) meta[e] = make_int4(sc[e], sp[e], so[e], 0);
}

// attn[slot,h,p] = softmax_p( q[slot,h,:].kp[p-slab][slot,hd] / 8 ), kp h16 slabs of stride M4
__global__ __launch_bounds__(256) void k_scores(const float* __restrict__ q, const h16* __restrict__ kp,
                                                float* __restrict__ attn, const int4* __restrict__ meta)
{
  const int gw = blockIdx.x * 4 + (threadIdx.x >> 6), ln = threadIdx.x & 63;
  const int n = gw >> 4, hh = gw & 15;
  if (n >= meta->y) return;
  const float qv = q[(long)n * 1024 + hh * 64 + ln];
  float s[8];
  #pragma unroll
  for (int p = 0; p < 8; p++) {
    float t = qv * (float)kp[(long)p * 4194304 + (long)n * 1024 + hh * 64 + ln];
    s[p] = wred(t) * 0.125f;
  }
  if (ln == 0) {
    float mx = s[0];
    #pragma unroll
    for (int p = 1; p < 8; p++) mx = fmaxf(mx, s[p]);
    float ex[8], sum = 0.f;
    #pragma unroll
    for (int p = 0; p < 8; p++) { ex[p] = expf(s[p] - mx); sum += ex[p]; }
    const float inv = 1.0f / sum;
    #pragma unroll
    for (int p = 0; p < 8; p++) attn[(long)n * 128 + hh * 8 + p] = ex[p] * inv;
  }
}

// o[slot,hd] = sum_p attn[slot,h,p]*vp[p-slab][slot,hd] -> h16 (non-split chain)
__global__ void k_omix2(const float* __restrict__ attn, const h16* __restrict__ vp,
                        h16* __restrict__ oh, const int4* __restrict__ meta)
{
  const long gid = (long)blockIdx.x * 256 + threadIdx.x;  // 4M
  const int n = gid >> 10, hd = gid & 1023, hh = hd >> 6;
  if (n >= meta->y) return;
  const float* a = attn + (long)n * 128 + hh * 8;
  float o = 0.f;
  #pragma unroll
  for (int p = 0; p < 8; p++) o += a[p] * (float)vp[(long)p * 4194304 + (long)n * 1024 + hd];
  oh[gid] = (h16)o;
}

#define GEMM3(SPL, EPI, MODE, GRID, ...) do { \
  if (SPL) gemm_k<true,  EPI, MODE><<<GRID, 256, 0, stream>>>(__VA_ARGS__); \
  else     gemm_k<false, EPI, MODE><<<GRID, 256, 0, stream>>>(__VA_ARGS__); } while (0)
#define GEMM256(SPL, EPI, MODE, GRID, ...) do { \
  if (SPL) gemm256_k<true,  EPI, MODE><<<GRID, 512, 0, stream>>>(__VA_ARGS__); \
  else     gemm256_k<false, EPI, MODE><<<GRID, 512, 0, stream>>>(__VA_ARGS__); } while (0)

extern "C" void kernel_launch(void* const* d_in, const int* in_sizes, int n_in,
                              void* d_out, int out_size, void* d_ws, size_t ws_size,
                              hipStream_t stream)
{
  (void)in_sizes; (void)n_in; (void)out_size; (void)ws_size;
  const int*   idx   = (const int*)  d_in[0];
  const float* cap   = (const float*)d_in[1];
  const float* emb   = (const float*)d_in[2];
  const float* headw = (const float*)d_in[3];
  const float* ln1g  = (const float*)d_in[4];
  const float* ln1b  = (const float*)d_in[5];
  const float* ln2g  = (const float*)d_in[6];
  const float* ln2b  = (const float*)d_in[7];
  const float* lnog  = (const float*)d_in[8];
  const float* lnob  = (const float*)d_in[9];
  const float* aWr   = (const float*)d_in[10];
  const float* aWk   = (const float*)d_in[11];
  const float* aWv   = (const float*)d_in[12];
  const float* aWo   = (const float*)d_in[13];
  const float* adec  = (const float*)d_in[14];
  const float* cwd   = (const float*)d_in[15];
  const float* cWa   = (const float*)d_in[16];
  const float* bWd   = (const float*)d_in[17];
  const float* bWu   = (const float*)d_in[18];
  const float* eWkw  = (const float*)d_in[19];
  const float* eWvw  = (const float*)d_in[20];
  const float* confr = (const float*)d_in[21];
  const float* tWq   = (const float*)d_in[22];
  const float* tWkk  = (const float*)d_in[23];
  const float* tWv   = (const float*)d_in[24];
  const float* tWo   = (const float*)d_in[25];
  const float* conft = (const float*)d_in[26];
  float* out = (float*)d_out;

  char* ws = (char*)d_ws;
  size_t off = 0;
  auto alloc = [&](size_t n) -> char* {
    off = (off + 255) & ~(size_t)255;
    char* p = ws + off; off += n; return p;
  };
  const long M1 = 1048576, M4 = 4194304;

  h16* attWh = (h16*)alloc(8 * M1 * 2);
  h16* attWl = (h16*)alloc(8 * M1 * 2);
  h16* eWkh  = (h16*)alloc(12 * M4 * 2);
  h16* eWkl  = (h16*)alloc(6 * M4 * 2);
  h16* eWvh  = (h16*)alloc(12 * M4 * 2);
  h16* eWvl  = (h16*)alloc(6 * M4 * 2);
  h16* tWh   = (h16*)alloc(16 * M1 * 2);     // layout: [lj=0..3][mat: q,k,v,o]
  h16* headh = (h16*)alloc(32768000ull * 2);
  h16* wdh   = (h16*)alloc(131072 * 2);
  h16* wuph  = (h16*)alloc(524288 * 2);
  h16* wupl  = (h16*)alloc(524288 * 2);
  h16* foldKh = (h16*)alloc(1048576 * 2);    // [hd=1024][j*512 + p*64 + r]
  h16* foldKl = (h16*)alloc(1048576 * 2);
  h16* foldVh = (h16*)alloc(1048576 * 2);
  h16* foldVl = (h16*)alloc(1048576 * 2);
  h16* s1h   = (h16*)alloc(2 * M4 * 2);      // seg 0 general; seg j for o-outputs
  h16* s1l   = (h16*)alloc(M4 * 2);
  h16* hh_   = (h16*)alloc(M4 * 2);
  h16* hl_   = (h16*)alloc(M4 * 2);
  h16* uh    = (h16*)alloc(262144 * 2);
  h16* ul    = (h16*)alloc(262144 * 2);
  float* x    = (float*)alloc(M4 * 4);
  float* vfir = (float*)alloc(M4 * 4);
  float* rkv  = (float*)alloc(3 * M4 * 4);        // fused r|k|v, [4096][3072]
  float* st   = (float*)alloc(M4 * 4);
  float* hf   = (float*)alloc(M4 * 4);
  float* qf   = (float*)alloc(2 * M4 * 4);        // q per transformer expert j
  char* big   = alloc(167772160);                 // 160MB union: hid hi/lo arena | kp/vp h16 slabs
  h16* hidh   = (h16*)big;                        // <=9984 rows x 4096 x 2B = 78MB
  h16* hidl   = (h16*)(big + 83886080ull);        // offset 80MiB
  h16* kpH    = (h16*)big;                        // 16 slabs x M4 h16 = 128MB
  float* carry = (float*)alloc(65536 * 4);
  float* gate  = (float*)alloc(32768 * 4);
  float* uf    = (float*)alloc(262144 * 4);
  float* attn  = (float*)alloc(2 * 524288 * 4);
  int*   cnt8  = (int*)alloc(32);
  int4*  metaA = (int4*)alloc(16 * 16);
  int*   lists = (int*)alloc(8 * 4224 * 4);
  int*   mmap  = (int*)alloc(64 * 4);

  // ---------- weight conversion ----------
  k_tsplit4<true><<<dim3(16, 16, 8), 256, 0, stream>>>(aWr, aWk, aWv, aWo, 0, attWh, attWl, 1024, 1024);
  k_tsplit<true ><<<dim3(64, 16, 6), 256, 0, stream>>>(eWkw, M4, eWkh, eWkl, M4, 1024, 4096);
  k_tsplit<false><<<dim3(64, 16, 6), 256, 0, stream>>>(eWkw + 6 * M4, M4, eWkh + 6 * M4, nullptr, M4, 1024, 4096);
  k_tsplit<true ><<<dim3(16, 64, 6), 256, 0, stream>>>(eWvw, M4, eWvh, eWvl, M4, 4096, 1024);
  k_tsplit<false><<<dim3(16, 64, 6), 256, 0, stream>>>(eWvw + 6 * M4, M4, eWvh + 6 * M4, nullptr, M4, 4096, 1024);
  k_tsplit4<false><<<dim3(16, 16, 16), 256, 0, stream>>>(tWq, tWkk, tWv, tWo, 0, tWh, nullptr, 1024, 1024);
  k_tsplit<false><<<dim3(500, 16, 1), 256, 0, stream>>>(headw, 0, headh, nullptr, 0, 1024, 32000);
  k_tsplit<false><<<dim3(1, 16, 1), 256, 0, stream>>>(bWd, 0, wdh, nullptr, 0, 1024, 64);
  hipMemsetAsync(wdh + 65536, 0, 65536 * 2, stream);   // pad Bt rows 64..127 with zeros
  k_split<<<512, 256, 0, stream>>>(bWu, wuph, wupl);

  // ---------- forward ----------
  k_embed<<<4096, 256, 0, stream>>>(idx, emb, x);

  for (int l = 0; l < 2; l++) {
    const bool SE = (l == 0);           // FFN expert path split only on layer 0
    // --- TimeMix (split: feeds routing); fused r|k|v GEMM, N=3072 ---
    k_ln<<<4096, 256, 0, stream>>>(x, ln1g + l * 1024, ln1b + l * 1024, nullptr, s1h, s1l);
    GEMM3(true, EPI_WRITE, 0, dim3(32, 24),
          s1h, s1l, 1024, 0, attWh + (l * 4) * M1, attWl + (l * 4) * M1, 1024, 0,
          rkv, 3072, 0, nullptr, nullptr, 0, 1024, 0, nullptr, 0, nullptr, 0, nullptr, 0, 0);
    k_vfix<<<4096, 256, 0, stream>>>(rkv, vfir, l == 0 ? 0 : 1);
    k_scan1<<<256, 256, 0, stream>>>(rkv, adec + l * 1024, carry);
    k_scan2<<<16, 256, 0, stream>>>(adec + l * 1024, carry);
    k_scan3<<<256, 256, 0, stream>>>(rkv, adec + l * 1024, carry, st);
    k_attin<<<4096, 256, 0, stream>>>(rkv, st, s1h, s1l);
    GEMM3(true, EPI_ADD, 0, dim3(32, 8),
          s1h, s1l, 1024, 0, attWh + (l * 4 + 3) * M1, attWl + (l * 4 + 3) * M1, 1024, 0,
          x, 1024, 0, nullptr, nullptr, 0, 1024, 0, nullptr, 0, nullptr, 0, nullptr, 0, 0);
    // --- routing + token lists ---
    k_ln<<<4096, 256, 0, stream>>>(x, ln2g + l * 1024, ln2b + l * 1024, hf, hh_, hl_);
    k_route<<<1024, 256, 0, stream>>>(hf, confr + l * 6144, conft + l * 2048, cwd + l * 1024, cWa + l * 8192, cap + l * 8, gate);
    hipMemsetAsync(cnt8, 0, 32, stream);
    k_build<<<16, 256, 0, stream>>>(gate, cnt8, lists);
    k_meta<<<1, 256, 0, stream>>>(cnt8, metaA, lists, mmap);
    // --- bridge: u = (h + state) @ Wdown (non-split) ---
    k_addsplit<<<4096, 256, 0, stream>>>(hf, st, s1h, s1l);
    GEMM3(false, EPI_WRITE, 0, dim3(32, 1),
          s1h, nullptr, 1024, 0, wdh, nullptr, 1024, 0,
          uf, 64, 0, nullptr, nullptr, 0, 1024, 64, nullptr, 0, nullptr, 0, nullptr, 0, 0);
    k_split<<<256, 256, 0, stream>>>(uf, uh, ul);
    // --- FFN experts: 256-tile arena gather->sqrelu, then 256-tile split-K(4) scatter ---
    GEMM256(SE, EPI_SQRELU, 3, dim3(40, 16),
            hh_, hl_, 1024, eWkh + l * 6 * M4, eWkl, 1024, M4,
            nullptr, 0, hidh, SE ? hidl : nullptr, 4096,
            1024, nullptr, 0, metaA, lists, 4224, mmap);
    GEMM256(SE, EPI_SCATTER, 4, dim3(40, 4, 4),
            hidh, hidl, 4096, eWvh + l * 6 * M4, eWvl, 4096, M4,
            x, 1024, nullptr, nullptr, 0,
            1024, gate, 8, metaA, lists, 4224, mmap);
    // --- transformer experts, batched over j (non-split chain) ---
    // folds: K and V, each z=2 over j -> foldK/V [hd][j*512+p*64+r]
    GEMM3(false, EPI_TSPLIT, 0, dim3(4, 8, 2),
          wuph, nullptr, 1024, 0, tWh + (l * 8 + 1) * M1, nullptr, 1024, 4 * M1,
          nullptr, 0, 0, foldKh, foldKl, 1024, 1024, 0, nullptr, 0, nullptr, 0, nullptr, 0, 512);
    GEMM3(false, EPI_TSPLIT, 0, dim3(4, 8, 2),
          wuph, nullptr, 1024, 0, tWh + (l * 8 + 2) * M1, nullptr, 1024, 4 * M1,
          nullptr, 0, 0, foldVh, foldVl, 1024, 1024, 0, nullptr, 0, nullptr, 0, nullptr, 0, 512);
    // q for both j: z=2 (MODE 1, per-z meta/list)
    GEMM3(false, EPI_WRITE, 1, dim3(32, 8, 2),
          hh_, nullptr, 1024, 0, tWh + (l * 8 + 0) * M1, nullptr, 1024, 4 * M1,
          qf, 1024, M4, nullptr, nullptr, 0, 1024, 0, nullptr, 0,
          metaA + 6, 1, lists + 6 * 4224, 4224, 0);
    // kp for both j: z=16 (MODE 6), h16 slabs [z][slot][hd]
    GEMM3(false, EPI_WRITEH, 6, dim3(32, 8, 16),
          uh, nullptr, 64, 0, foldKh, nullptr, 1024, 64,
          nullptr, 0, 0, kpH, nullptr, 1024, 64, 0, nullptr, 0,
          metaA + 6, 1, lists + 6 * 4224, 4224, M4);
    for (int j = 0; j < 2; j++)
      k_scores<<<16384, 256, 0, stream>>>(qf + (long)j * M4, kpH + (long)j * 8 * M4,
                                          attn + (long)j * 524288, metaA + 6 + j);
    // vp for both j (overwrites kpH)
    GEMM3(false, EPI_WRITEH, 6, dim3(32, 8, 16),
          uh, nullptr, 64, 0, foldVh, nullptr, 1024, 64,
          nullptr, 0, 0, kpH, nullptr, 1024, 64, 0, nullptr, 0,
          metaA + 6, 1, lists + 6 * 4224, 4224, M4);
    for (int j = 0; j < 2; j++)
      k_omix2<<<16384, 256, 0, stream>>>(attn + (long)j * 524288, kpH + (long)j * 8 * M4,
                                         s1h + (long)j * M4, metaA + 6 + j);
    // x[tok] += gate * (o @ tWo): both j + 4 K-slices in one dispatch (MODE 5)
    GEMM3(false, EPI_SCATTER, 5, dim3(32, 8, 8),
          s1h, nullptr, 1024, M4, tWh + (l * 8 + 3) * M1, nullptr, 1024, 4 * M1,
          x, 1024, 0, nullptr, nullptr, 0, 256, 0, gate + 6, 8,
          metaA + 6, 1, lists + 6 * 4224, 4224, 0);
  }

  // --- final LN + head (plain fp16, 128-tile: best measured config) ---
  k_ln<<<4096, 256, 0, stream>>>(x, lnog, lnob, nullptr, s1h, s1l);
  GEMM3(false, EPI_WRITE, 0, dim3(32, 250),
        s1h, nullptr, 1024, 0, headh, nullptr, 1024, 0,
        out, 32000, 0, nullptr, nullptr, 0, 1024, 0, nullptr, 0, nullptr, 0, nullptr, 0, 0);
}